// Round 6
// baseline (44.363 us; speedup 1.0000x reference)
//
#include <hip/hip_runtime.h>
#include <hip/hip_bf16.h>

#define DM 2048
#define BB 64
#define SS 32
#define CC 8
#define KP 8    // k-split across blocks
#define KR 256  // k-range per block

typedef __attribute__((ext_vector_type(8))) short short8;
typedef __attribute__((ext_vector_type(4))) short short4v;
typedef __attribute__((ext_vector_type(4))) float f32x4;

static __device__ __forceinline__ short f2bf(float f) {
  union { __hip_bfloat16 h; short s; } u;
  u.h = __float2bfloat16(f);  // RNE; compiler fuses to v_cvt_pk_bf16_f32
  return u.s;
}

// K1: u16[b][k] = bf16(sum_c controls[c][b][k]).  grid 128 x 256
__global__ void k1_sum_bf16(const float* __restrict__ controls,
                            short* __restrict__ u16) {
  const int idx = blockIdx.x * 256 + threadIdx.x;  // 32768 = 64b * 512 kq
  const int b = idx >> 9;
  const int k = (idx & 511) * 4;
  float4 s = make_float4(0.f, 0.f, 0.f, 0.f);
#pragma unroll
  for (int c = 0; c < CC; ++c) {
    const float4 v = *reinterpret_cast<const float4*>(
        controls + ((size_t)c * BB + b) * DM + k);
    s.x += v.x; s.y += v.y; s.z += v.z; s.w += v.w;
  }
  short4v o = {f2bf(s.x), f2bf(s.y), f2bf(s.z), f2bf(s.w)};
  *reinterpret_cast<short4v*>(u16 + (size_t)b * DM + k) = o;
}

// MFMA GEMM: part[kp][b][e] = sum_{k in kp} A[b][k] * W[e][k]
// A: bf16 row-major [64][2048] (L2-resident).  W: fp32 row-major, cvt on fly.
// One m-tile per wave (16b x 16e x 256k): 1 MFMA + 3 loads per k-step,
// single f32x4 accumulator. Block = 4 waves = 4 m-tiles sharing the same
// 16 W rows (4-way L2 reuse inside the block; W still read once from HBM).
// grid 1024: etile = bid&127 (16 e), kp = bid>>7.  4096 waves = 4/SIMD.
// No LDS, no barriers, no wave-uniform memory operands.
__global__ __launch_bounds__(256, 4) void gemm_mfma(
    const short* __restrict__ abf, const float* __restrict__ w,
    float* __restrict__ part) {
  const int t    = threadIdx.x;
  const int lane = t & 63;
  const int wv   = t >> 6;                 // m-tile: b-rows wv*16..+15
  const int e0   = (blockIdx.x & 127) * 16;
  const int kp   = blockIdx.x >> 7;
  const int k0   = kp * KR;

  const int r  = lane & 15;        // m for A-frag, n(=e) for B-frag
  const int kc = (lane >> 4) * 8;  // k sub-offset within 32

  f32x4 acc = {0.f, 0.f, 0.f, 0.f};

  const float* wp = w + (size_t)(e0 + r) * DM + k0 + kc;
  const short* ap = abf + (size_t)(wv * 16 + r) * DM + k0 + kc;

#pragma unroll
  for (int s = 0; s < KR / 32; ++s) {
    const int ko = s * 32;
    const float4 wlo = *reinterpret_cast<const float4*>(wp + ko);
    const float4 whi = *reinterpret_cast<const float4*>(wp + ko + 4);
    const short8 a0 = *reinterpret_cast<const short8*>(ap + ko);
    short8 bfrag;
    bfrag[0] = f2bf(wlo.x); bfrag[1] = f2bf(wlo.y);
    bfrag[2] = f2bf(wlo.z); bfrag[3] = f2bf(wlo.w);
    bfrag[4] = f2bf(whi.x); bfrag[5] = f2bf(whi.y);
    bfrag[6] = f2bf(whi.z); bfrag[7] = f2bf(whi.w);
    acc = __builtin_amdgcn_mfma_f32_16x16x32_bf16(a0, bfrag, acc, 0, 0, 0);
  }

  // D: lane l reg j -> b = wv*16 + (l>>4)*4 + j, e = e0 + (l&15)
  const int brow = wv * 16 + (lane >> 4) * 4;
  float* pb = part + ((size_t)kp * BB + brow) * DM + e0 + r;
#pragma unroll
  for (int j = 0; j < 4; ++j) pb[(size_t)j * DM] = acc[j];
}

// R1: v16[b][e] = bf16(sum_kp part[kp][b][e] + 8*bias[e]).  grid 128 x 256
__global__ void reduce_bias_bf16(const float* __restrict__ part,
                                 const float* __restrict__ bias,
                                 short* __restrict__ v16) {
  const int idx = blockIdx.x * 256 + threadIdx.x;  // 32768
  const int b = idx >> 9;
  const int e = (idx & 511) * 4;
  const float4 bb = *reinterpret_cast<const float4*>(bias + e);
  float4 s = make_float4(8.f * bb.x, 8.f * bb.y, 8.f * bb.z, 8.f * bb.w);
#pragma unroll
  for (int kp = 0; kp < KP; ++kp) {
    const float4 p = *reinterpret_cast<const float4*>(
        part + ((size_t)kp * BB + b) * DM + e);
    s.x += p.x; s.y += p.y; s.z += p.z; s.w += p.w;
  }
  short4v o = {f2bf(s.x), f2bf(s.y), f2bf(s.z), f2bf(s.w)};
  *reinterpret_cast<short4v*>(v16 + (size_t)b * DM + e) = o;
}

// K4 fused: out[b][s][e] = seq[b][s][e] + (sum_kp part[kp][b][e] + 8*bo[e])
// grid 512: b = bid>>3, e-eighth = bid&7 (256 e). block 256:
// thread -> e-quad (t&63), s-group s0 = t>>6, 8 s-iterations.
__global__ void k4_fused(const float* __restrict__ seq,
                         const float* __restrict__ part,
                         const float* __restrict__ bias,
                         float* __restrict__ out) {
  const int b  = blockIdx.x >> 3;
  const int e  = (blockIdx.x & 7) * 256 + (threadIdx.x & 63) * 4;
  const int s0 = (threadIdx.x >> 6) * 8;
  const float4 bb = *reinterpret_cast<const float4*>(bias + e);
  float4 pv = make_float4(8.f * bb.x, 8.f * bb.y, 8.f * bb.z, 8.f * bb.w);
#pragma unroll
  for (int kp = 0; kp < KP; ++kp) {
    const float4 p = *reinterpret_cast<const float4*>(
        part + ((size_t)kp * BB + b) * DM + e);
    pv.x += p.x; pv.y += p.y; pv.z += p.z; pv.w += p.w;
  }
  const size_t base = (size_t)b * SS * DM + e;
#pragma unroll
  for (int i = 0; i < 8; ++i) {
    const size_t off = base + (size_t)(s0 + i) * DM;
    const float4 q = *reinterpret_cast<const float4*>(seq + off);
    *reinterpret_cast<float4*>(out + off) =
        make_float4(q.x + pv.x, q.y + pv.y, q.z + pv.z, q.w + pv.w);
  }
}

extern "C" void kernel_launch(void* const* d_in, const int* in_sizes, int n_in,
                              void* d_out, int out_size, void* d_ws,
                              size_t ws_size, hipStream_t stream) {
  const float* seq      = (const float*)d_in[0];
  const float* controls = (const float*)d_in[1];
  // d_in[2..5] = Wq, bq, Wk, bk — mathematically unused (softmax over size-1 axis == 1)
  const float* Wv = (const float*)d_in[6];
  const float* bv = (const float*)d_in[7];
  const float* Wo = (const float*)d_in[8];
  const float* bo = (const float*)d_in[9];
  float* out = (float*)d_out;

  char* ws = (char*)d_ws;
  short* u16  = (short*)(ws);                    // 256 KB bf16 [64][2048]
  short* v16  = (short*)(ws + (256ull << 10));   // 256 KB bf16 [64][2048]
  float* part = (float*)(ws + (1024ull << 10));  // 4 MB fp32 [8][64][2048]

  k1_sum_bf16<<<128, 256, 0, stream>>>(controls, u16);
  gemm_mfma<<<1024, 256, 0, stream>>>(u16, Wv, part);
  reduce_bias_bf16<<<128, 256, 0, stream>>>(part, bv, v16);
  gemm_mfma<<<1024, 256, 0, stream>>>(v16, Wo, part);
  k4_fused<<<512, 256, 0, stream>>>(seq, part, bo, out);
}

// Round 7
// 39.090 us; speedup vs baseline: 1.1349x; 1.1349x over previous
//
#include <hip/hip_runtime.h>
#include <hip/hip_bf16.h>

#define DM 2048
#define BB 64
#define SS 32
#define CC 8
#define KP 16   // k-split across blocks
#define KR 128  // k-range per block (KP*KR = DM)

typedef __attribute__((ext_vector_type(8))) short short8;
typedef __attribute__((ext_vector_type(4))) short short4v;
typedef __attribute__((ext_vector_type(4))) float f32x4;

static __device__ __forceinline__ short f2bf(float f) {
  union { __hip_bfloat16 h; short s; } u;
  u.h = __float2bfloat16(f);  // RNE; compiler fuses to v_cvt_pk_bf16_f32
  return u.s;
}

// K1: u16[b][k] = bf16(sum_c controls[c][b][k]).  grid 256 x 128 (1 blk/CU)
__global__ void k1_sum_bf16(const float* __restrict__ controls,
                            short* __restrict__ u16) {
  const int idx = blockIdx.x * 128 + threadIdx.x;  // 32768 = 64b * 512 kq
  const int b = idx >> 9;
  const int k = (idx & 511) * 4;
  float4 s = make_float4(0.f, 0.f, 0.f, 0.f);
#pragma unroll
  for (int c = 0; c < CC; ++c) {
    const float4 v = *reinterpret_cast<const float4*>(
        controls + ((size_t)c * BB + b) * DM + k);
    s.x += v.x; s.y += v.y; s.z += v.z; s.w += v.w;
  }
  short4v o = {f2bf(s.x), f2bf(s.y), f2bf(s.z), f2bf(s.w)};
  *reinterpret_cast<short4v*>(u16 + (size_t)b * DM + k) = o;
}

// MFMA GEMM: part[kp][b][e] = sum_{k in kp} A[b][k] * W[e][k]
// A: bf16 row-major [64][2048] (L2-resident).  W: fp32 row-major, cvt on fly.
// r5 wave shape (proven fastest): wave = 64b x 16e x KRk — 4 m-tile accs
// share one W fragment: 6 VMEM / 4 MFMA per k-32 step, fully unrolled
// (4 steps, 24 loads in flight). Block = 4 waves = 4 e-tiles (64 e).
// grid 512 = 32 eblk x 16 kp -> 2048 waves = 2/SIMD (fixes r5's 1/SIMD;
// avoids r6's W-instr x4 redundancy). No LDS, no barriers, no uniform loads.
__global__ __launch_bounds__(256, 2) void gemm_mfma(
    const short* __restrict__ abf, const float* __restrict__ w,
    float* __restrict__ part) {
  const int t    = threadIdx.x;
  const int lane = t & 63;
  const int wv   = t >> 6;
  const int e0   = (blockIdx.x & 31) * 64 + wv * 16;
  const int kp   = blockIdx.x >> 5;
  const int k0   = kp * KR;

  const int r  = lane & 15;        // m for A-frags, n(=e) for B-frag
  const int kc = (lane >> 4) * 8;  // k sub-offset within 32

  f32x4 acc0 = {0.f, 0.f, 0.f, 0.f}, acc1 = {0.f, 0.f, 0.f, 0.f};
  f32x4 acc2 = {0.f, 0.f, 0.f, 0.f}, acc3 = {0.f, 0.f, 0.f, 0.f};

  const float* wp = w + (size_t)(e0 + r) * DM + k0 + kc;
  const short* ap = abf + (size_t)r * DM + k0 + kc;

#pragma unroll
  for (int s = 0; s < KR / 32; ++s) {
    const int ko = s * 32;
    const float4 wlo = *reinterpret_cast<const float4*>(wp + ko);
    const float4 whi = *reinterpret_cast<const float4*>(wp + ko + 4);
    const short8 a0 = *reinterpret_cast<const short8*>(ap + ko);
    const short8 a1 = *reinterpret_cast<const short8*>(ap + (size_t)16 * DM + ko);
    const short8 a2 = *reinterpret_cast<const short8*>(ap + (size_t)32 * DM + ko);
    const short8 a3 = *reinterpret_cast<const short8*>(ap + (size_t)48 * DM + ko);
    short8 bfrag;
    bfrag[0] = f2bf(wlo.x); bfrag[1] = f2bf(wlo.y);
    bfrag[2] = f2bf(wlo.z); bfrag[3] = f2bf(wlo.w);
    bfrag[4] = f2bf(whi.x); bfrag[5] = f2bf(whi.y);
    bfrag[6] = f2bf(whi.z); bfrag[7] = f2bf(whi.w);
    acc0 = __builtin_amdgcn_mfma_f32_16x16x32_bf16(a0, bfrag, acc0, 0, 0, 0);
    acc1 = __builtin_amdgcn_mfma_f32_16x16x32_bf16(a1, bfrag, acc1, 0, 0, 0);
    acc2 = __builtin_amdgcn_mfma_f32_16x16x32_bf16(a2, bfrag, acc2, 0, 0, 0);
    acc3 = __builtin_amdgcn_mfma_f32_16x16x32_bf16(a3, bfrag, acc3, 0, 0, 0);
  }

  // D: lane l reg j -> b = base + (l>>4)*4 + j, e = e0 + (l&15)
  const int brow = (lane >> 4) * 4;
  float* pb = part + ((size_t)kp * BB) * DM + e0 + r;
#pragma unroll
  for (int j = 0; j < 4; ++j) {
    pb[(size_t)(brow + j) * DM]      = acc0[j];
    pb[(size_t)(brow + j + 16) * DM] = acc1[j];
    pb[(size_t)(brow + j + 32) * DM] = acc2[j];
    pb[(size_t)(brow + j + 48) * DM] = acc3[j];
  }
}

// R1: v16[b][e] = bf16(sum_kp part[kp][b][e] + 8*bias[e]).  grid 256 x 128
__global__ void reduce_bias_bf16(const float* __restrict__ part,
                                 const float* __restrict__ bias,
                                 short* __restrict__ v16) {
  const int idx = blockIdx.x * 128 + threadIdx.x;  // 32768
  const int b = idx >> 9;
  const int e = (idx & 511) * 4;
  const float4 bb = *reinterpret_cast<const float4*>(bias + e);
  float4 s = make_float4(8.f * bb.x, 8.f * bb.y, 8.f * bb.z, 8.f * bb.w);
#pragma unroll
  for (int kp = 0; kp < KP; ++kp) {
    const float4 p = *reinterpret_cast<const float4*>(
        part + ((size_t)kp * BB + b) * DM + e);
    s.x += p.x; s.y += p.y; s.z += p.z; s.w += p.w;
  }
  short4v o = {f2bf(s.x), f2bf(s.y), f2bf(s.z), f2bf(s.w)};
  *reinterpret_cast<short4v*>(v16 + (size_t)b * DM + e) = o;
}

// K4 fused: out[b][s][e] = seq[b][s][e] + (sum_kp part[kp][b][e] + 8*bo[e])
// grid 512: b = bid>>3, e-eighth = bid&7 (256 e). block 256:
// thread -> e-quad (t&63), s-group s0 = t>>6, 8 s-iterations.
__global__ void k4_fused(const float* __restrict__ seq,
                         const float* __restrict__ part,
                         const float* __restrict__ bias,
                         float* __restrict__ out) {
  const int b  = blockIdx.x >> 3;
  const int e  = (blockIdx.x & 7) * 256 + (threadIdx.x & 63) * 4;
  const int s0 = (threadIdx.x >> 6) * 8;
  const float4 bb = *reinterpret_cast<const float4*>(bias + e);
  float4 pv = make_float4(8.f * bb.x, 8.f * bb.y, 8.f * bb.z, 8.f * bb.w);
#pragma unroll
  for (int kp = 0; kp < KP; ++kp) {
    const float4 p = *reinterpret_cast<const float4*>(
        part + ((size_t)kp * BB + b) * DM + e);
    pv.x += p.x; pv.y += p.y; pv.z += p.z; pv.w += p.w;
  }
  const size_t base = (size_t)b * SS * DM + e;
#pragma unroll
  for (int i = 0; i < 8; ++i) {
    const size_t off = base + (size_t)(s0 + i) * DM;
    const float4 q = *reinterpret_cast<const float4*>(seq + off);
    *reinterpret_cast<float4*>(out + off) =
        make_float4(q.x + pv.x, q.y + pv.y, q.z + pv.z, q.w + pv.w);
  }
}

extern "C" void kernel_launch(void* const* d_in, const int* in_sizes, int n_in,
                              void* d_out, int out_size, void* d_ws,
                              size_t ws_size, hipStream_t stream) {
  const float* seq      = (const float*)d_in[0];
  const float* controls = (const float*)d_in[1];
  // d_in[2..5] = Wq, bq, Wk, bk — mathematically unused (softmax over size-1 axis == 1)
  const float* Wv = (const float*)d_in[6];
  const float* bv = (const float*)d_in[7];
  const float* Wo = (const float*)d_in[8];
  const float* bo = (const float*)d_in[9];
  float* out = (float*)d_out;

  char* ws = (char*)d_ws;
  short* u16  = (short*)(ws);                    // 256 KB bf16 [64][2048]
  short* v16  = (short*)(ws + (256ull << 10));   // 256 KB bf16 [64][2048]
  float* part = (float*)(ws + (1024ull << 10));  // 8 MB fp32 [16][64][2048]

  k1_sum_bf16<<<256, 128, 0, stream>>>(controls, u16);
  gemm_mfma<<<512, 256, 0, stream>>>(u16, Wv, part);
  reduce_bias_bf16<<<256, 128, 0, stream>>>(part, bv, v16);
  gemm_mfma<<<512, 256, 0, stream>>>(v16, Wo, part);
  k4_fused<<<512, 256, 0, stream>>>(seq, part, bo, out);
}